// Round 13
// baseline (127.945 us; speedup 1.0000x reference)
//
#include <hip/hip_runtime.h>
#include <hip/hip_bf16.h>
#include <math.h>

// Problem constants (B=4096 rows, D=768 features)
#define B_ROWS 4096
#define D_DIM  768

// R13 = R11's direct-to-register GEMM (128x128, 4 waves, 64x64/wave — the
// VGPR-cheapest shape) + TRIPLE-buffered register prefetch (loads issued 3
// K-tiles ahead) + R12's verified L2 panel fix (3 MB/XCD).
// Model (R11 vs R12): delivery = waves/CU x in-flight/wave (Little's law);
// R11 16.9 TB/s @ 8 loads/wave, R12 12 TB/s (fatter acc, fewer waves).
// Tripling the prefetch depth on the cheap shape raises in-flight/CU 2-3x
// without crossing the 128-VGPR occupancy cliff.
#define BM 128
#define BN 128
#define BK 32
#define NKT (D_DIM / BK)        // 24 K-tiles
#define KT_STRIDE (B_ROWS * 32) // ushorts per BK=32 K-tile block in Pb/Tb
#define NBLK ((B_ROWS / BM) * (B_ROWS / BN))   // 32*32 = 1024 workgroups

typedef __attribute__((ext_vector_type(8))) short bf16x8;  // 8 bf16 = 4 VGPRs (MFMA A/B frag)
typedef __attribute__((ext_vector_type(4))) float f32x4;   // MFMA C/D frag

__device__ __forceinline__ unsigned short f32_to_bf16(float x) {
    // round-to-nearest-even; inputs are finite normals
    unsigned int u = __float_as_uint(x);
    return (unsigned short)((u + 0x7fffu + ((u >> 16) & 1u)) >> 16);
}

// K1: per-row stats + fp32->bf16 conversion into the BLOCKED, PRE-SWIZZLED
// layout Pb[kt32][row][slot] (kt32 = K-tile of 32 elems, 64-B rows, 16-B
// chunk at slot = chunk ^ ((row>>1)&3)).  Unchanged since R8 (verified).
__global__ void __launch_bounds__(256) rowstats_kernel(
    const float* __restrict__ P, const float* __restrict__ T,
    unsigned short* __restrict__ Pb, unsigned short* __restrict__ Tb,
    float* __restrict__ p_sq, float* __restrict__ t_sq,
    float* __restrict__ diagl, float* __restrict__ magr,
    float* __restrict__ rowsum)
{
    const int wave = threadIdx.x >> 6, lane = threadIdx.x & 63;
    const int i = blockIdx.x * 4 + wave;
    const f32x4* prow = (const f32x4*)(P + (size_t)i * D_DIM);
    const f32x4* trow = (const f32x4*)(T + (size_t)i * D_DIM);
    const int swz = (i >> 1) & 3;

    float psq = 0.f, tsq = 0.f, cr = 0.f, l1 = 0.f, tm = 0.f;
    #pragma unroll
    for (int u = 0; u < 3; ++u) {         // 192 float4 per row / 64 lanes
        const int c4 = u * 64 + lane;
        f32x4 p = prow[c4], t = trow[c4];
        #pragma unroll
        for (int k = 0; k < 4; ++k) {
            psq += p[k] * p[k]; tsq += t[k] * t[k]; cr += p[k] * t[k];
            l1 += fabsf(p[k] - t[k]); tm += fabsf(t[k]);
        }
        // blocked-swizzled destination
        const int kt  = c4 >> 3;                 // 8 float4 = 32 elems per tile
        const int cc  = (c4 >> 1) & 3;           // 16-B chunk within tile row
        const int sub = c4 & 1;                  // 8-B half of the chunk
        const size_t doff = (size_t)kt * KT_STRIDE + (size_t)i * 32
                          + (size_t)(((cc ^ swz) << 3) + (sub << 2));
        *(ushort4*)(Pb + doff) = make_ushort4(f32_to_bf16(p[0]), f32_to_bf16(p[1]),
                                              f32_to_bf16(p[2]), f32_to_bf16(p[3]));
        *(ushort4*)(Tb + doff) = make_ushort4(f32_to_bf16(t[0]), f32_to_bf16(t[1]),
                                              f32_to_bf16(t[2]), f32_to_bf16(t[3]));
    }
    #pragma unroll
    for (int m = 1; m < 64; m <<= 1) {
        psq += __shfl_xor(psq, m, 64);
        tsq += __shfl_xor(tsq, m, 64);
        cr  += __shfl_xor(cr,  m, 64);
        l1  += __shfl_xor(l1,  m, 64);
        tm  += __shfl_xor(tm,  m, 64);
    }
    if (lane == 0) {
        p_sq[i] = psq;
        t_sq[i] = tsq;
        float sq = fmaxf(psq + tsq - 2.0f * cr, 0.0f);
        diagl[i] = -sqrtf(sq) * 10.0f;    // logit_ii = -dist/0.1 (the LSE shift)
        magr[i]  = l1 / tm;
        rowsum[i] = 0.0f;
    }
}

// K2: bf16-MFMA cross GEMM + LSE epilogue, direct-to-register, 3-deep
// register pipeline.  128x128 block, 4 waves (2x2), per-wave 64x64.
//
// Fragment load (per wave, per K-tile): 4 A + 4 B global_load_dwordx4; lane
// (row16,quad) reads 16 B at base + row*64B + (quad^((row16>>1)&3))*16B ==
// 1 KB contiguous in the blocked layout (XOR undoes the pre-swizzle).
//
// K-loop: THREE named frag sets; loads for tile t+3 are issued right after
// the MFMAs that consume set (t mod 3), so 2-3 tiles (16-24 loads/wave) are
// in flight at all times.  Static indexing only (rule #20).  No barriers,
// no LDS; compiler inserts the vmcnt waits from register dependencies.
__global__ void __launch_bounds__(256, 2) lse_gemm_kernel(
    const unsigned short* __restrict__ Pb, const unsigned short* __restrict__ Tb,
    const float* __restrict__ p_sq, const float* __restrict__ t_sq,
    const float* __restrict__ diagl, float* __restrict__ rowsum)
{
    const int tid  = threadIdx.x;
    const int lane = tid & 63, wave = tid >> 6;

    // XCD-aware swizzle (bijective over 1024 blocks): tile grid 32x32.
    // Each XCD covers 16(ti) x 8(tj) in TWO passes of 8x8 tiles ->
    // per-pass panel A 8*128 rows (1.5 MB) + B 8*128 rows (1.5 MB) = 3 MB
    // < 4 MB L2 (R11's single-pass 4.5 MB panel spilled: FETCH 24.4 MB).
    const int flat = blockIdx.x;
    const int xcd  = flat & 7;
    const int s    = flat >> 3;                      // 0..127: slot within XCD
    const int pass = s >> 6;                         // 0..1
    const int w    = s & 63;                         // 0..63
    const int ti   = ((xcd & 1) << 4) + (pass << 3) + (w >> 3);   // 0..31
    const int tj   = ((xcd >> 1) << 3) + (w & 7);                 // 0..31
    const int i0   = ti * BM, j0 = tj * BN;

    // compute mapping: 2x2 wave grid, per-wave output 64(M) x 64(N)
    const int wm = wave >> 1, wn = wave & 1;
    const int row16 = lane & 15, quad = lane >> 4;
    const int slot  = quad ^ ((row16 >> 1) & 3);     // chunk-XOR de-swizzle

    // per-lane frag pointers (ushort units), advanced by KT_STRIDE per tile
    const unsigned short* ap[4];
    const unsigned short* bp[4];
    #pragma unroll
    for (int mt = 0; mt < 4; ++mt)
        ap[mt] = Pb + (size_t)(i0 + wm * 64 + mt * 16 + row16) * 32 + slot * 8;
    #pragma unroll
    for (int nt = 0; nt < 4; ++nt)
        bp[nt] = Tb + (size_t)(j0 + wn * 64 + nt * 16 + row16) * 32 + slot * 8;

    f32x4 acc[4][4];
    #pragma unroll
    for (int a = 0; a < 4; ++a)
        #pragma unroll
        for (int b = 0; b < 4; ++b)
            acc[a][b] = (f32x4){0.f, 0.f, 0.f, 0.f};

    // three named register frag sets (static indexing; no runtime-indexed sel)
    bf16x8 a0[4], b0[4], a1[4], b1[4], a2[4], b2[4];

#define LOADSET(A, B, T_)                                            \
    {                                                                \
        const size_t o_ = (size_t)(T_) * KT_STRIDE;                  \
        _Pragma("unroll")                                            \
        for (int f = 0; f < 4; ++f) {                                \
            A[f] = *(const bf16x8*)(ap[f] + o_);                     \
            B[f] = *(const bf16x8*)(bp[f] + o_);                     \
        }                                                            \
    }
#define MFMASET(A, B)                                                \
    __builtin_amdgcn_s_setprio(1);                                   \
    _Pragma("unroll")                                                \
    for (int mt = 0; mt < 4; ++mt)                                   \
        _Pragma("unroll")                                            \
        for (int nt = 0; nt < 4; ++nt)                               \
            acc[mt][nt] = __builtin_amdgcn_mfma_f32_16x16x32_bf16(   \
                A[mt], B[nt], acc[mt][nt], 0, 0, 0);                 \
    __builtin_amdgcn_s_setprio(0);

    // prologue: fill the 3-deep pipeline
    LOADSET(a0, b0, 0)
    LOADSET(a1, b1, 1)
    LOADSET(a2, b2, 2)

    // 24 tiles, 3 per loop body (24 % 3 == 0).  Loads for t+3 are issued
    // immediately after the MFMAs that free set (t mod 3).
    for (int t = 0; t < NKT; t += 3) {
        MFMASET(a0, b0)
        if (t + 3 < NKT) LOADSET(a0, b0, t + 3)
        MFMASET(a1, b1)
        if (t + 4 < NKT) LOADSET(a1, b1, t + 4)
        MFMASET(a2, b2)
        if (t + 5 < NKT) LOADSET(a2, b2, t + 5)
    }
#undef LOADSET
#undef MFMASET

    // Epilogue: C/D layout col=lane&15, row=quad*4+reg (m89/m91-verified).
    // term = exp(logit_ij - logit_ii) via exp2f; max shifted log2-exp ~99 < 127.
    const float NT_LOG2E = -14.4269504089f;   // -(1/TEMP) * log2(e)
    const float LOG2E    = 1.44269504089f;
    float tsq_l[4];
    #pragma unroll
    for (int nt = 0; nt < 4; ++nt)
        tsq_l[nt] = t_sq[j0 + wn * 64 + nt * 16 + row16];

    #pragma unroll
    for (int mt = 0; mt < 4; ++mt) {
        #pragma unroll
        for (int r = 0; r < 4; ++r) {
            const int i = i0 + wm * 64 + mt * 16 + quad * 4 + r;
            const float psq = p_sq[i];
            const float c0  = -diagl[i] * LOG2E;  // -logit_ii in log2 domain
            float sfin = 0.f;
            #pragma unroll
            for (int nt = 0; nt < 4; ++nt) {
                float c  = acc[mt][nt][r];
                float sq = fmaxf(fmaf(-2.0f, c, psq + tsq_l[nt]), 0.0f);
                float d  = sqrtf(sq);
                float y  = fmaf(d, NT_LOG2E, c0);  // (logit-logit_ii)*log2e
                sfin += exp2f(y);
            }
            #pragma unroll
            for (int m = 1; m < 16; m <<= 1) sfin += __shfl_xor(sfin, m, 64);
            if (row16 == 0) atomicAdd(&rowsum[i], sfin);
        }
    }
}

// K3: final reduction to the 3 output scalars (separate dispatch — fusion
// into the GEMM measured +42 us via the per-block fence/straggler tail, R7).
__global__ void __launch_bounds__(256) finalize_kernel(
    const float* __restrict__ rowsum, const float* __restrict__ magr,
    float* __restrict__ out)
{
    const int tid = threadIdx.x;
    double sc = 0.0, sm = 0.0;
    for (int i = tid; i < B_ROWS; i += 256) {
        sc += log((double)rowsum[i]);   // loss_i = log sum_j exp(logit_ij - logit_ii)
        sm += (double)magr[i];
    }
    #pragma unroll
    for (int m = 1; m < 64; m <<= 1) {
        sc += __shfl_xor(sc, m, 64);
        sm += __shfl_xor(sm, m, 64);
    }
    __shared__ double red[4][2];
    const int wave = tid >> 6, lane = tid & 63;
    if (lane == 0) { red[wave][0] = sc; red[wave][1] = sm; }
    __syncthreads();
    if (tid == 0) {
        sc = red[0][0] + red[1][0] + red[2][0] + red[3][0];
        sm = red[0][1] + red[1][1] + red[2][1] + red[3][1];
        double lc = sc / (double)B_ROWS;
        double lm = sm / (double)B_ROWS;
        out[0] = (float)(0.5 * lc + 0.5 * lm);  // LOSS_SCALE=1, LAMBD=0.5
        out[1] = (float)lc;
        out[2] = (float)lm;
    }
}

extern "C" void kernel_launch(void* const* d_in, const int* in_sizes, int n_in,
                              void* d_out, int out_size, void* d_ws, size_t ws_size,
                              hipStream_t stream) {
    const float* P = (const float*)d_in[0];   // predicted [4096,768] fp32
    const float* T = (const float*)d_in[1];   // target    [4096,768] fp32
    float* out = (float*)d_out;               // 3 fp32 scalars

    // Workspace: Pb at ws+80KB (128-B aligned); nothing before Pb/Tb
    // (R2/R4/R5's 16-B shift lesson).
    char* ws = (char*)d_ws;
    float* rowsum = (float*)ws;               ws += B_ROWS * sizeof(float);
    float* p_sq   = (float*)ws;               ws += B_ROWS * sizeof(float);
    float* t_sq   = (float*)ws;               ws += B_ROWS * sizeof(float);
    float* diagl  = (float*)ws;               ws += B_ROWS * sizeof(float);
    float* magr   = (float*)ws;               ws += B_ROWS * sizeof(float);
    unsigned short* Pb = (unsigned short*)ws; ws += (size_t)B_ROWS * D_DIM * 2;
    unsigned short* Tb = (unsigned short*)ws;

    rowstats_kernel<<<B_ROWS / 4, 256, 0, stream>>>(
        P, T, Pb, Tb, p_sq, t_sq, diagl, magr, rowsum);
    lse_gemm_kernel<<<NBLK, 256, 0, stream>>>(
        Pb, Tb, p_sq, t_sq, diagl, rowsum);
    finalize_kernel<<<1, 256, 0, stream>>>(rowsum, magr, out);
}

// Round 14
// 112.092 us; speedup vs baseline: 1.1414x; 1.1414x over previous
//
#include <hip/hip_runtime.h>
#include <hip/hip_bf16.h>
#include <math.h>

// Problem constants (B=4096 rows, D=768 features)
#define B_ROWS 4096
#define D_DIM  768

// R14 = byte-exact revert to R8, the session-best composition (114.3 us):
//   - 128x256 staged GEMM, BK=32, 4 waves, NBUF=3 (72 KB -> 2 blocks/CU),
//     depth-2 prefetch, counted vmcnt(6)   [GEMM <= 46.8 us]
//   - blocked pre-swizzled Pb/Tb rowstats  [1-KB contiguous staging reads]
//   - separate finalize dispatch           [in-GEMM fusion cost +42 us, R7]
// R13 (3-deep register pipeline) fired its falsifier (78 us: in-order vmcnt
// retirement makes deep queues a liability); R11 (2-deep reg-direct) ties
// this GEMM at 46.5 but measured worse total.  Both GEMM families converge
// at 46-48 us — the practical floor of this session's technique set.
#define BM 128
#define BN 256
#define BK 32
#define NKT (D_DIM / BK)        // 24 K-tiles
#define NBUF 3
#define KT_STRIDE (B_ROWS * 32) // ushorts per K-tile block in Pb/Tb layout
#define A_USH (BM * BK)         // 4096 ushorts (8 KB) A region per buffer
#define AB_USH ((BM + BN) * BK) // 12288 ushorts (24 KB) per buffer
#define NBLK ((B_ROWS / BM) * (B_ROWS / BN))   // 32*16 = 512 workgroups

typedef __attribute__((ext_vector_type(8))) short bf16x8;  // 8 bf16 = 4 VGPRs (MFMA A/B frag)
typedef __attribute__((ext_vector_type(4))) float f32x4;   // MFMA C/D frag

__device__ __forceinline__ unsigned short f32_to_bf16(float x) {
    // round-to-nearest-even; inputs are finite normals
    unsigned int u = __float_as_uint(x);
    return (unsigned short)((u + 0x7fffu + ((u >> 16) & 1u)) >> 16);
}

// async global->LDS, 16 B per lane. LDS dest is WAVE-UNIFORM base; HW writes
// lane L's 16 B at base + L*16 (m97/m104-verified semantics).
__device__ __forceinline__ void async_copy16(const unsigned short* g, unsigned short* l) {
    __builtin_amdgcn_global_load_lds(
        (const __attribute__((address_space(1))) unsigned int*)g,
        (__attribute__((address_space(3))) unsigned int*)l,
        16, 0, 0);
}

// K1: per-row stats + fp32->bf16 conversion into a BLOCKED, PRE-SWIZZLED
// layout:  Pb[kt][row][slot]  (kt = K-tile of 32 elems, 64-B rows, 16-B
// chunk stored at slot = chunk ^ ((row>>1)&3)).  Staging reads in the GEMM
// are then fully contiguous 1 KB per global_load_lds instr, and the LDS
// bank swizzle is baked into the data (source-perm == read-perm involution,
// rule #21).  Harness-verified R2/R4/R8 (absmax 0).
__global__ void __launch_bounds__(256) rowstats_kernel(
    const float* __restrict__ P, const float* __restrict__ T,
    unsigned short* __restrict__ Pb, unsigned short* __restrict__ Tb,
    float* __restrict__ p_sq, float* __restrict__ t_sq,
    float* __restrict__ diagl, float* __restrict__ magr,
    float* __restrict__ rowsum)
{
    const int wave = threadIdx.x >> 6, lane = threadIdx.x & 63;
    const int i = blockIdx.x * 4 + wave;
    const f32x4* prow = (const f32x4*)(P + (size_t)i * D_DIM);
    const f32x4* trow = (const f32x4*)(T + (size_t)i * D_DIM);
    const int swz = (i >> 1) & 3;

    float psq = 0.f, tsq = 0.f, cr = 0.f, l1 = 0.f, tm = 0.f;
    #pragma unroll
    for (int u = 0; u < 3; ++u) {         // 192 float4 per row / 64 lanes
        const int c4 = u * 64 + lane;
        f32x4 p = prow[c4], t = trow[c4];
        #pragma unroll
        for (int k = 0; k < 4; ++k) {
            psq += p[k] * p[k]; tsq += t[k] * t[k]; cr += p[k] * t[k];
            l1 += fabsf(p[k] - t[k]); tm += fabsf(t[k]);
        }
        // blocked-swizzled destination
        const int kt  = c4 >> 3;                 // 8 float4 = 32 elems per tile
        const int cc  = (c4 >> 1) & 3;           // 16-B chunk within tile row
        const int sub = c4 & 1;                  // 8-B half of the chunk
        const size_t doff = (size_t)kt * KT_STRIDE + (size_t)i * 32
                          + (size_t)(((cc ^ swz) << 3) + (sub << 2));
        *(ushort4*)(Pb + doff) = make_ushort4(f32_to_bf16(p[0]), f32_to_bf16(p[1]),
                                              f32_to_bf16(p[2]), f32_to_bf16(p[3]));
        *(ushort4*)(Tb + doff) = make_ushort4(f32_to_bf16(t[0]), f32_to_bf16(t[1]),
                                              f32_to_bf16(t[2]), f32_to_bf16(t[3]));
    }
    #pragma unroll
    for (int m = 1; m < 64; m <<= 1) {
        psq += __shfl_xor(psq, m, 64);
        tsq += __shfl_xor(tsq, m, 64);
        cr  += __shfl_xor(cr,  m, 64);
        l1  += __shfl_xor(l1,  m, 64);
        tm  += __shfl_xor(tm,  m, 64);
    }
    if (lane == 0) {
        p_sq[i] = psq;
        t_sq[i] = tsq;
        float sq = fmaxf(psq + tsq - 2.0f * cr, 0.0f);
        diagl[i] = -sqrtf(sq) * 10.0f;    // logit_ii = -dist/0.1 (the LSE shift)
        magr[i]  = l1 / tm;
        rowsum[i] = 0.0f;
    }
}

// K2: bf16-MFMA cross GEMM + LSE epilogue (R8's exact kernel).
//
// vmcnt accounting (uniform per wave): 6 stage instrs/tile/wave (A:2, B:4).
// Depth-2 prefetch: at the end-of-tile wait, outstanding = tiles t+1 (6) and
// t+2 (6); vmcnt(6) retires exactly tile t+1.  Buffers: tile t lives in
// buf t%3; stage(t+2) writes (t+2)%3 == (t-1)%3 whose readers finished at
// the end-of-(t-1) barrier.  Never vmcnt(0) in the main loop.
__global__ void __launch_bounds__(256, 2) lse_gemm_kernel(
    const unsigned short* __restrict__ Pb, const unsigned short* __restrict__ Tb,
    const float* __restrict__ p_sq, const float* __restrict__ t_sq,
    const float* __restrict__ diagl, float* __restrict__ rowsum)
{
    __shared__ __align__(16) unsigned short S[NBUF][AB_USH];  // 72 KB

    const int tid  = threadIdx.x;
    const int lane = tid & 63, wave = tid >> 6;

    // XCD-aware swizzle: 512 wgs round-robin flat%8 over XCDs; give XCD x a
    // contiguous 8x8 tile chunk (A 1.5 MB + B 3 MB ~ L2-resident).  Tile grid
    // is 32(M) x 16(N); XCDs arranged 4x2 over it.  Bijective over 512 blocks.
    const int flat = blockIdx.x;
    const int xcd  = flat & 7;
    const int s    = flat >> 3;                      // 0..63: slot within XCD
    const int ti   = ((xcd >> 1) << 3) + (s >> 3);   // 0..31
    const int tj   = ((xcd & 1) << 3) + (s & 7);     // 0..15
    const int i0   = ti * BM, j0 = tj * BN;

    // compute mapping: 2x2 wave grid, per-wave output 64(M) x 128(N)
    const int wm = wave >> 1, wn = wave & 1;
    const int row16 = lane & 15, quad = lane >> 4;
    const int slot  = quad ^ ((row16 >> 1) & 3);     // chunk-XOR de-swizzle

    // fragment LDS offsets (ushort units); (R>>1)&3 depends only on row16
    // since all row bases are multiples of 16.
    int aoff[4], boff[8];
    #pragma unroll
    for (int mt = 0; mt < 4; ++mt)
        aoff[mt] = (wm * 64 + mt * 16 + row16) * BK + (slot << 3);
    #pragma unroll
    for (int nt = 0; nt < 8; ++nt)
        boff[nt] = A_USH + (wn * 128 + nt * 16 + row16) * BK + (slot << 3);

    // staging: 24 instrs/tile split 6 per wave. Wave w covers A 16-row
    // groups {2w, 2w+1} and B groups {4w..4w+3}.  Each instr = 1 KB
    // contiguous (16 rows x 64 B), per-lane addr = base + lane*16 B ==
    // the linear LDS write pattern; data pre-swizzled by rowstats.
    const unsigned short* gpA[2];
    const unsigned short* gpB[4];
    int lbA[2], lbB[4];
    #pragma unroll
    for (int k = 0; k < 2; ++k) {
        const int grp = 2 * wave + k;               // 0..7
        gpA[k] = Pb + (size_t)(i0 + grp * 16) * 32 + lane * 8;
        lbA[k] = grp * 512;
    }
    #pragma unroll
    for (int k = 0; k < 4; ++k) {
        const int grp = 4 * wave + k;               // 0..15
        gpB[k] = Tb + (size_t)(j0 + grp * 16) * 32 + lane * 8;
        lbB[k] = A_USH + grp * 512;
    }

    f32x4 acc[4][8];
    #pragma unroll
    for (int a = 0; a < 4; ++a)
        #pragma unroll
        for (int b = 0; b < 8; ++b)
            acc[a][b] = (f32x4){0.f, 0.f, 0.f, 0.f};

    auto stage = [&](int t) {
        const size_t koff = (size_t)t * KT_STRIDE;
        unsigned short* dst = &S[t % NBUF][0];
        #pragma unroll
        for (int k = 0; k < 2; ++k) async_copy16(gpA[k] + koff, dst + lbA[k]);
        #pragma unroll
        for (int k = 0; k < 4; ++k) async_copy16(gpB[k] + koff, dst + lbB[k]);
    };
    auto compute = [&](int t) {
        const unsigned short* buf = &S[t % NBUF][0];
        bf16x8 a[4], b[8];
        #pragma unroll
        for (int mt = 0; mt < 4; ++mt) a[mt] = *(const bf16x8*)(buf + aoff[mt]);
        #pragma unroll
        for (int nt = 0; nt < 8; ++nt) b[nt] = *(const bf16x8*)(buf + boff[nt]);
        __builtin_amdgcn_s_setprio(1);
        #pragma unroll
        for (int mt = 0; mt < 4; ++mt)
            #pragma unroll
            for (int nt = 0; nt < 8; ++nt)
                acc[mt][nt] = __builtin_amdgcn_mfma_f32_16x16x32_bf16(
                    a[mt], b[nt], acc[mt][nt], 0, 0, 0);
        __builtin_amdgcn_s_setprio(0);
    };

    // prologue: stage tiles 0,1 (12 loads/wave); vmcnt(6) -> tile 0 landed
    stage(0);
    stage(1);
    asm volatile("s_waitcnt vmcnt(6)" ::: "memory");
    __builtin_amdgcn_s_barrier();

    // main loop: t = 0..21.  stage(t+2) early -> full iteration to land.
    for (int t = 0; t < NKT - 2; ++t) {
        stage(t + 2);
        compute(t);
        asm volatile("s_waitcnt vmcnt(6)" ::: "memory");  // tile t+1 landed
        __builtin_amdgcn_s_barrier();
    }
    // drain: tile 22 ready (waited in last iter), then 23.
    compute(NKT - 2);
    asm volatile("s_waitcnt vmcnt(0)" ::: "memory");
    __builtin_amdgcn_s_barrier();
    compute(NKT - 1);

    // Epilogue: C/D layout col=lane&15, row=quad*4+reg (m89/m91-verified).
    // term = exp(logit_ij - logit_ii) via exp2f; max shifted log2-exp ~99 < 127.
    const float NT_LOG2E = -14.4269504089f;   // -(1/TEMP) * log2(e)
    const float LOG2E    = 1.44269504089f;
    float tsq_l[8];
    #pragma unroll
    for (int nt = 0; nt < 8; ++nt)
        tsq_l[nt] = t_sq[j0 + wn * 128 + nt * 16 + row16];

    #pragma unroll
    for (int mt = 0; mt < 4; ++mt) {
        #pragma unroll
        for (int r = 0; r < 4; ++r) {
            const int i = i0 + wm * 64 + mt * 16 + quad * 4 + r;
            const float psq = p_sq[i];
            const float c0  = -diagl[i] * LOG2E;  // -logit_ii in log2 domain
            float sfin = 0.f;
            #pragma unroll
            for (int nt = 0; nt < 8; ++nt) {
                float c  = acc[mt][nt][r];
                float sq = fmaxf(fmaf(-2.0f, c, psq + tsq_l[nt]), 0.0f);
                float d  = sqrtf(sq);
                float y  = fmaf(d, NT_LOG2E, c0);  // (logit-logit_ii)*log2e
                sfin += exp2f(y);
            }
            #pragma unroll
            for (int m = 1; m < 16; m <<= 1) sfin += __shfl_xor(sfin, m, 64);
            if (row16 == 0) atomicAdd(&rowsum[i], sfin);
        }
    }
}

// K3: final reduction to the 3 output scalars (separate dispatch — the fused
// in-GEMM version cost ~42 us via per-block __threadfence L2 writebacks, R7).
__global__ void __launch_bounds__(256) finalize_kernel(
    const float* __restrict__ rowsum, const float* __restrict__ magr,
    float* __restrict__ out)
{
    const int tid = threadIdx.x;
    double sc = 0.0, sm = 0.0;
    for (int i = tid; i < B_ROWS; i += 256) {
        sc += log((double)rowsum[i]);   // loss_i = log sum_j exp(logit_ij - logit_ii)
        sm += (double)magr[i];
    }
    #pragma unroll
    for (int m = 1; m < 64; m <<= 1) {
        sc += __shfl_xor(sc, m, 64);
        sm += __shfl_xor(sm, m, 64);
    }
    __shared__ double red[4][2];
    const int wave = tid >> 6, lane = tid & 63;
    if (lane == 0) { red[wave][0] = sc; red[wave][1] = sm; }
    __syncthreads();
    if (tid == 0) {
        sc = red[0][0] + red[1][0] + red[2][0] + red[3][0];
        sm = red[0][1] + red[1][1] + red[2][1] + red[3][1];
        double lc = sc / (double)B_ROWS;
        double lm = sm / (double)B_ROWS;
        out[0] = (float)(0.5 * lc + 0.5 * lm);  // LOSS_SCALE=1, LAMBD=0.5
        out[1] = (float)lc;
        out[2] = (float)lm;
    }
}

extern "C" void kernel_launch(void* const* d_in, const int* in_sizes, int n_in,
                              void* d_out, int out_size, void* d_ws, size_t ws_size,
                              hipStream_t stream) {
    const float* P = (const float*)d_in[0];   // predicted [4096,768] fp32
    const float* T = (const float*)d_in[1];   // target    [4096,768] fp32
    float* out = (float*)d_out;               // 3 fp32 scalars

    // Workspace: Pb at ws+80KB (128-B aligned); no slots before Pb/Tb
    // (R2/R4/R5's 16-B shift lesson).
    char* ws = (char*)d_ws;
    float* rowsum = (float*)ws;               ws += B_ROWS * sizeof(float);
    float* p_sq   = (float*)ws;               ws += B_ROWS * sizeof(float);
    float* t_sq   = (float*)ws;               ws += B_ROWS * sizeof(float);
    float* diagl  = (float*)ws;               ws += B_ROWS * sizeof(float);
    float* magr   = (float*)ws;               ws += B_ROWS * sizeof(float);
    unsigned short* Pb = (unsigned short*)ws; ws += (size_t)B_ROWS * D_DIM * 2;
    unsigned short* Tb = (unsigned short*)ws;

    rowstats_kernel<<<B_ROWS / 4, 256, 0, stream>>>(
        P, T, Pb, Tb, p_sq, t_sq, diagl, magr, rowsum);
    lse_gemm_kernel<<<NBLK, 256, 0, stream>>>(
        Pb, Tb, p_sq, t_sq, diagl, rowsum);
    finalize_kernel<<<1, 256, 0, stream>>>(rowsum, magr, out);
}